// Round 1
// baseline (68.460 us; speedup 1.0000x reference)
//
#include <hip/hip_runtime.h>

// H2I stencil: out[w] = 1 - clip(max_{r=0..15}(pad(x)[w+r+1] - (r+1)/10) - x[w], 0, 1)
// Row-local (W axis), right-padded with -1000. Shapes: (16,1,512,512) fp32.
//
// Memory-bound: 16 MiB in + 16 MiB out. One thread = 4 consecutive elements
// (float4 in/out). Algebraic rewrite y[j] = x[j] - 0.1*j turns the 4 windows
// into a shared max core C = max(y[4..16]) + 2-3 extra maxes per output.

#define IM 512
#define PADV -1000.0f

__global__ __launch_bounds__(256) void h2i_kernel(const float* __restrict__ in,
                                                  float* __restrict__ out,
                                                  int n) {
    int tid = blockIdx.x * blockDim.x + threadIdx.x;
    int e0 = tid * 4;
    if (e0 >= n) return;

    int w0 = e0 & (IM - 1);          // position in row (row width 512, pow2)
    const float* rowp = in + (e0 - w0);

    // Load x[w0 .. w0+19] as 5 aligned float4 chunks. w0 % 4 == 0 and
    // IM % 4 == 0 => each chunk is fully in-row or fully in the pad region.
    float x[20];
#pragma unroll
    for (int k = 0; k < 5; ++k) {
        int col = w0 + 4 * k;
        float4 v;
        if (col < IM) {
            v = *reinterpret_cast<const float4*>(rowp + col);
        } else {
            v = make_float4(PADV, PADV, PADV, PADV);
        }
        x[4 * k + 0] = v.x;
        x[4 * k + 1] = v.y;
        x[4 * k + 2] = v.z;
        x[4 * k + 3] = v.w;
    }

    // y[j] = x[j] - 0.1*j  (local index). Then
    // compare_i = max_{j=i+1..i+16} y[j] + 0.1*i.
    float y[20];
#pragma unroll
    for (int j = 1; j < 20; ++j) {
        y[j] = x[j] - 0.1f * (float)j;
    }

    // Shared core: positions 4..16 appear in all four windows.
    float C = y[4];
#pragma unroll
    for (int j = 5; j <= 16; ++j) C = fmaxf(C, y[j]);
    float a2 = fmaxf(y[2], y[3]);    // shared by windows 0,1
    float b  = fmaxf(y[17], y[18]);  // shared by windows 2,3

    float m0 = fmaxf(fmaxf(C, y[1]), a2);           // y[1..16]
    float m1 = fmaxf(fmaxf(C, a2), y[17]) + 0.1f;   // y[2..17]
    float m2 = fmaxf(fmaxf(C, y[3]), b) + 0.2f;     // y[3..18]
    float m3 = fmaxf(fmaxf(C, b), y[19]) + 0.3f;    // y[4..19]

    float4 r;
    r.x = 1.0f - fminf(fmaxf(m0 - x[0], 0.0f), 1.0f);
    r.y = 1.0f - fminf(fmaxf(m1 - x[1], 0.0f), 1.0f);
    r.z = 1.0f - fminf(fmaxf(m2 - x[2], 0.0f), 1.0f);
    r.w = 1.0f - fminf(fmaxf(m3 - x[3], 0.0f), 1.0f);
    *reinterpret_cast<float4*>(out + e0) = r;
}

extern "C" void kernel_launch(void* const* d_in, const int* in_sizes, int n_in,
                              void* d_out, int out_size, void* d_ws, size_t ws_size,
                              hipStream_t stream) {
    const float* in = (const float*)d_in[0];
    float* out = (float*)d_out;
    int n = out_size;                       // 16*1*512*512 = 4194304
    int threads = 256;
    int blocks = (n / 4 + threads - 1) / threads;  // 4096
    h2i_kernel<<<blocks, threads, 0, stream>>>(in, out, n);
}

// Round 2
// 67.843 us; speedup vs baseline: 1.0091x; 1.0091x over previous
//
#include <hip/hip_runtime.h>

// H2I stencil: out[w] = 1 - clip(max_{r=0..15}(pad(x)[w+r+1] - (r+1)/10) - x[w], 0, 1)
// Row-local (W axis), right-padded with -1000. Shapes: (16,1,512,512) fp32.
//
// Memory-bound: 16 MiB in + 16 MiB out (HBM floor ~5.5 us @ 6.1 TB/s).
// One thread = 8 consecutive elements (two float4 out). Algebraic rewrite
// y[j] = x[j] - 0.1*j + prefix/suffix max factorization: each of the 8
// windows max(y[i+1..i+16]) = fmax(S[i+1], P[i+16]) with
// S[j] = max(y[j..16]) (suffix), P[j] = max(y[17..j]) (prefix).
// Nontemporal stores: output is write-once, keep it out of L2.

#define IM 512
#define PADV -1000.0f

typedef float v4f __attribute__((ext_vector_type(4)));

__global__ __launch_bounds__(256) void h2i_kernel(const float* __restrict__ in,
                                                  float* __restrict__ out,
                                                  int n) {
    int tid = blockIdx.x * blockDim.x + threadIdx.x;
    int e0 = tid * 8;
    if (e0 >= n) return;

    int w0 = e0 & (IM - 1);          // position in row (row width 512, pow2)
    const float* rowp = in + (e0 - w0);

    // Load x[w0 .. w0+23] as 6 aligned float4 chunks. w0 % 8 == 0 and
    // IM % 8 == 0 => each chunk is fully in-row or fully in the pad region.
    float x[24];
#pragma unroll
    for (int k = 0; k < 6; ++k) {
        int col = w0 + 4 * k;
        v4f v;
        if (col < IM) {
            v = *reinterpret_cast<const v4f*>(rowp + col);
        } else {
            v = (v4f){PADV, PADV, PADV, PADV};
        }
        x[4 * k + 0] = v.x;
        x[4 * k + 1] = v.y;
        x[4 * k + 2] = v.z;
        x[4 * k + 3] = v.w;
    }

    // y[j] = x[j] - 0.1*j (local index); window i needs max(y[i+1..i+16]).
    float y[24];
#pragma unroll
    for (int j = 1; j < 24; ++j) {
        y[j] = x[j] - 0.1f * (float)j;
    }

    // Suffix maxes S[j] = max(y[j..16]) for j = 8..1.
    float S[17];
    S[16] = y[16];
#pragma unroll
    for (int j = 15; j >= 1; --j) S[j] = fmaxf(y[j], S[j + 1]);

    // Prefix maxes P[j] = max(y[17..j]) for j = 17..23.
    float P[24];
    P[17] = y[17];
#pragma unroll
    for (int j = 18; j < 24; ++j) P[j] = fmaxf(P[j - 1], y[j]);

    float m[8];
    m[0] = S[1];
#pragma unroll
    for (int i = 1; i < 8; ++i) {
        m[i] = fmaxf(S[i + 1], P[16 + i]) + 0.1f * (float)i;
    }

    float r[8];
#pragma unroll
    for (int i = 0; i < 8; ++i) {
        r[i] = 1.0f - fminf(fmaxf(m[i] - x[i], 0.0f), 1.0f);
    }

    v4f lo = (v4f){r[0], r[1], r[2], r[3]};
    v4f hi = (v4f){r[4], r[5], r[6], r[7]};
    __builtin_nontemporal_store(lo, reinterpret_cast<v4f*>(out + e0));
    __builtin_nontemporal_store(hi, reinterpret_cast<v4f*>(out + e0 + 4));
}

extern "C" void kernel_launch(void* const* d_in, const int* in_sizes, int n_in,
                              void* d_out, int out_size, void* d_ws, size_t ws_size,
                              hipStream_t stream) {
    const float* in = (const float*)d_in[0];
    float* out = (float*)d_out;
    int n = out_size;                            // 16*1*512*512 = 4194304
    int threads = 256;
    int blocks = (n / 8 + threads - 1) / threads;  // 2048
    h2i_kernel<<<blocks, threads, 0, stream>>>(in, out, n);
}